// Round 9
// baseline (90.938 us; speedup 1.0000x reference)
//
#include <hip/hip_runtime.h>
#include <stdint.h>

typedef unsigned short u16;
typedef __attribute__((ext_vector_type(8))) short short8;
typedef __attribute__((ext_vector_type(4))) float f32x4;

#define BATCH 4
#define SEQ   2048
#define DIN   768
#define DK    128
#define DV    768
#define MTOT  (BATCH*SEQ)   // 8192
#define NQKV  1024          // 128 q + 128 k + 768 v

__device__ __forceinline__ u16 f2bf(float f) {
  union { float f; uint32_t u; } v; v.f = f;
  uint32_t r = v.u + 0x7FFFu + ((v.u >> 16) & 1u);
  return (u16)(r >> 16);
}
__device__ __forceinline__ float bf2f(u16 h) {
  union { uint32_t u; float f; } v; v.u = ((uint32_t)h) << 16;
  return v.f;
}

template<int N> __device__ __forceinline__ void wait_vmcnt() {
  if constexpr (N == 0) asm volatile("s_waitcnt vmcnt(0)" ::: "memory");
  else if constexpr (N == 5) asm volatile("s_waitcnt vmcnt(5)" ::: "memory");
  else if constexpr (N == 10) asm volatile("s_waitcnt vmcnt(10)" ::: "memory");
}

// ---------------- K0: prep = convert_x + pack weights/bias + zero rsum ----------------
__global__ __launch_bounds__(256) void prep(
    const float* __restrict__ x, u16* __restrict__ xb,
    const float* __restrict__ Wq, const float* __restrict__ bq,
    const float* __restrict__ Wk, const float* __restrict__ bk,
    const float* __restrict__ Wv, const float* __restrict__ bv,
    u16* __restrict__ WbT, float* __restrict__ biasP, float* __restrict__ rsum) {
  const float qs = 0.088388347648318447f;  // 1/sqrt(128)
  __shared__ u16 tile[64][72];
  int b = blockIdx.x;
  int tid = threadIdx.x;
  if (b < 6144) {               // convert x -> bf16
    int i = (b * 256 + tid) * 4;
    float4 v = *(const float4*)(x + i);
    u16 o[4] = { f2bf(v.x), f2bf(v.y), f2bf(v.z), f2bf(v.w) };
    *(uint2*)(xb + i) = *(const uint2*)o;
    return;
  }
  if (b >= 6144 + 192) {        // zero rsum (8 blocks x 1024 floats)
    int i = (b - 6144 - 192) * 1024 + tid * 4;
    *(float4*)(rsum + i) = make_float4(0.f, 0.f, 0.f, 0.f);
    return;
  }
  int bid2 = b - 6144;          // 0..191 : pack weights (12 x 16)
  int y   = bid2 / 12;
  int i0  = (bid2 - y * 12) * 64;
  const float* W; u16* dst; int ldw, nb; float sc;
  if (y < 2)      { W = Wq; dst = WbT;                      ldw = DK; sc = qs;   nb = y;     }
  else if (y < 4) { W = Wk; dst = WbT + (size_t)DK * DIN;   ldw = DK; sc = 1.0f; nb = y - 2; }
  else            { W = Wv; dst = WbT + (size_t)2*DK * DIN; ldw = DV; sc = 1.0f; nb = y - 4; }
  int n0 = nb * 64;
  if (i0 == 0 && y == 0) {
    for (int n = tid; n < NQKV; n += 256)
      biasP[n] = (n < DK) ? bq[n] * qs : (n < 2*DK ? bk[n - DK] : bv[n - 2*DK]);
  }
  int tr = tid >> 2;
  int tc = (tid & 3) * 16;
  const float* src = W + (size_t)(i0 + tr) * ldw + n0 + tc;
  u16 o[16];
#pragma unroll
  for (int u = 0; u < 16; u += 4) {
    float4 v = *(const float4*)(src + u);
    o[u] = f2bf(v.x * sc); o[u+1] = f2bf(v.y * sc); o[u+2] = f2bf(v.z * sc); o[u+3] = f2bf(v.w * sc);
  }
  *(uint4*)&tile[tr][tc]     = *(const uint4*)&o[0];
  *(uint4*)&tile[tr][tc + 8] = *(const uint4*)&o[8];
  __syncthreads();
  u16 tmp[16];
#pragma unroll
  for (int u = 0; u < 16; ++u) tmp[u] = tile[tc + u][tr];
  u16* d = dst + (size_t)(n0 + tr) * DIN + i0 + tc;
  *(uint4*)d       = *(const uint4*)&tmp[0];
  *(uint4*)(d + 8) = *(const uint4*)&tmp[8];
}

// ---------------- proj GEMM (2-phase dbuf): qkv projection ----------------
// n0<256 -> C0=qk bf16 [M][256]; n0>=256 -> C1=vT bf16 [BATCH][DV][SEQ] TRANSPOSED.
__global__ __launch_bounds__(512, 4) void gemm_proj(
    const u16* __restrict__ A, const u16* __restrict__ BT,
    u16* __restrict__ C0, u16* __restrict__ C1,
    const float* __restrict__ bias)
{
  const int NJ = 2, CH = 4, gx = 64;
  __shared__ u16 As[2][128][64];
  __shared__ u16 Bs[2][NJ * 64][64];
  const int tid = threadIdx.x;
  const int l   = tid & 63;
  const int wid = tid >> 6;
  const int wm  = wid >> 2;
  const int wn  = wid & 3;

  const int nwg = gridDim.x;
  const int cpx = nwg >> 3;
  const int bid = blockIdx.x;
  const int wg  = (bid & 7) * cpx + (bid >> 3);
  const int by  = wg / gx;
  const int bx  = wg - by * gx;
  const int m0  = bx * 128;
  const int n0  = by * (NJ * 64);

  f32x4 acc[4][NJ] = {};
  const int lr = l >> 3;
  const int lc = ((l & 7) ^ lr) * 8;
  const int ca = wid * CH;

  auto STAGE = [&](int buf, int k0) {
#pragma unroll
    for (int i = 0; i < CH; ++i) {
      int c = ca + i;
      if (c < 16) {
        const u16* src = A + (size_t)(m0 + c * 8 + lr) * DIN + k0 + lc;
        __builtin_amdgcn_global_load_lds(
            (const __attribute__((address_space(1))) unsigned int*)src,
            (__attribute__((address_space(3))) unsigned int*)&As[buf][c * 8][0],
            16, 0, 0);
      } else {
        int cb = c - 16;
        const u16* src = BT + (size_t)(n0 + cb * 8 + lr) * DIN + k0 + lc;
        __builtin_amdgcn_global_load_lds(
            (const __attribute__((address_space(1))) unsigned int*)src,
            (__attribute__((address_space(3))) unsigned int*)&Bs[buf][cb * 8][0],
            16, 0, 0);
      }
    }
  };

  STAGE(0, 0);
  __syncthreads();
  int cur = 0;
  for (int k0 = 0; k0 < DIN; k0 += 64) {
    if (k0 + 64 < DIN) STAGE(cur ^ 1, k0 + 64);
#pragma unroll
    for (int ks = 0; ks < 2; ++ks) {
      short8 af[4], bg[NJ];
#pragma unroll
      for (int i = 0; i < 4; ++i) {
        int row  = wm * 64 + i * 16 + (l & 15);
        int slot = (ks * 4 + (l >> 4)) ^ (row & 7);
        af[i] = *(const short8*)&As[cur][row][slot * 8];
      }
#pragma unroll
      for (int j = 0; j < NJ; ++j) {
        int row  = wn * (NJ * 16) + j * 16 + (l & 15);
        int slot = (ks * 4 + (l >> 4)) ^ (row & 7);
        bg[j] = *(const short8*)&Bs[cur][row][slot * 8];
      }
#pragma unroll
      for (int i = 0; i < 4; ++i)
#pragma unroll
        for (int j = 0; j < NJ; ++j)
          acc[i][j] = __builtin_amdgcn_mfma_f32_16x16x32_bf16(af[i], bg[j], acc[i][j], 0, 0, 0);
    }
    __syncthreads();
    cur ^= 1;
  }

  const int rbase = (l >> 4) * 4;
  const int cl    = l & 15;
#pragma unroll
  for (int i = 0; i < 4; ++i) {
#pragma unroll
    for (int j = 0; j < NJ; ++j) {
      int col = n0 + wn * (NJ * 16) + j * 16 + cl;
      int row0 = m0 + wm * 64 + i * 16 + rbase;
      float bv_ = bias[col];
      if (n0 < 256) {
#pragma unroll
        for (int q = 0; q < 4; ++q)
          C0[(size_t)(row0 + q) * 256 + col] = f2bf(acc[i][j][q] + bv_);
      } else {
        int b = row0 >> 11, t = row0 & 2047;
        u16 o[4];
#pragma unroll
        for (int q = 0; q < 4; ++q) o[q] = f2bf(acc[i][j][q] + bv_);
        *(uint2*)&C1[((size_t)b * DV + (col - 256)) * SEQ + t] = *(const uint2*)o;
      }
    }
  }
}

// ---------------- K3: S-GEMM single-stage: P = exp(q_s @ k^T) + partial row-sums ----------------
__global__ __launch_bounds__(512, 4) void sgemm_exp(
    const u16* __restrict__ qk, u16* __restrict__ P, float* __restrict__ rsum)
{
  __shared__ u16 As[128][128];
  __shared__ u16 Bs[128][128];
  const int tid = threadIdx.x;
  const int l   = tid & 63;
  const int wid = tid >> 6;
  const int wm  = wid >> 2;
  const int wn  = wid & 3;

  const int nwg = gridDim.x;      // 1024
  const int cpx = nwg >> 3;
  const int bid = blockIdx.x;
  const int wg  = (bid & 7) * cpx + (bid >> 3);
  const int z   = wg >> 8;
  const int rem = wg & 255;
  const int by  = rem >> 4;
  const int bx  = rem & 15;
  const int m0  = bx * 128;
  const int n0  = by * 128;

  const u16* A  = qk + (size_t)z * SEQ * 256;
  const u16* BT = qk + DK + (size_t)z * SEQ * 256;

  const int rin  = l >> 4;
  const int s16  = l & 15;
#pragma unroll
  for (int i = 0; i < 8; ++i) {
    int c = wid * 8 + i;
    if (c < 32) {
      int r = c * 4 + rin;
      int gs = s16 ^ (r & 7);
      const u16* src = A + (size_t)(m0 + r) * 256 + gs * 8;
      __builtin_amdgcn_global_load_lds(
          (const __attribute__((address_space(1))) unsigned int*)src,
          (__attribute__((address_space(3))) unsigned int*)&As[c * 4][0],
          16, 0, 0);
    } else {
      int cb = c - 32;
      int r = cb * 4 + rin;
      int gs = s16 ^ (r & 7);
      const u16* src = BT + (size_t)(n0 + r) * 256 + gs * 8;
      __builtin_amdgcn_global_load_lds(
          (const __attribute__((address_space(1))) unsigned int*)src,
          (__attribute__((address_space(3))) unsigned int*)&Bs[cb * 4][0],
          16, 0, 0);
    }
  }
  __syncthreads();

  f32x4 acc[4][2] = {};
#pragma unroll
  for (int ks = 0; ks < 4; ++ks) {
    short8 af[4], bg[2];
#pragma unroll
    for (int i = 0; i < 4; ++i) {
      int row  = wm * 64 + i * 16 + (l & 15);
      int slot = (ks * 4 + (l >> 4)) ^ (row & 7);
      af[i] = *(const short8*)&As[row][slot * 8];
    }
#pragma unroll
    for (int j = 0; j < 2; ++j) {
      int row  = wn * 32 + j * 16 + (l & 15);
      int slot = (ks * 4 + (l >> 4)) ^ (row & 7);
      bg[j] = *(const short8*)&Bs[row][slot * 8];
    }
#pragma unroll
    for (int i = 0; i < 4; ++i)
#pragma unroll
      for (int j = 0; j < 2; ++j)
        acc[i][j] = __builtin_amdgcn_mfma_f32_16x16x32_bf16(af[i], bg[j], acc[i][j], 0, 0, 0);
  }

  const int rbase = (l >> 4) * 4;
  const int cl    = l & 15;
  u16* Pz = P + (size_t)z * SEQ * SEQ;
  float ex[4][2][4];
#pragma unroll
  for (int i = 0; i < 4; ++i)
#pragma unroll
    for (int j = 0; j < 2; ++j) {
      int col  = n0 + wn * 32 + j * 16 + cl;
      int row0 = m0 + wm * 64 + i * 16 + rbase;
#pragma unroll
      for (int q = 0; q < 4; ++q) {
        u16 h = f2bf(__expf(acc[i][j][q]));
        ex[i][j][q] = bf2f(h);                 // rounded value, matches P numerics
        Pz[(size_t)(row0 + q) * SEQ + col] = h;
      }
    }
  // partial row sums over this wave's 32 cols -> atomicAdd
  float* rs_g = rsum + (size_t)z * SEQ;
#pragma unroll
  for (int i = 0; i < 4; ++i)
#pragma unroll
    for (int q = 0; q < 4; ++q) {
      float s = ex[i][0][q] + ex[i][1][q];
      s += __shfl_xor(s, 1, 64);
      s += __shfl_xor(s, 2, 64);
      s += __shfl_xor(s, 4, 64);
      s += __shfl_xor(s, 8, 64);
      if (cl == 0) atomicAdd(&rs_g[m0 + wm * 64 + i * 16 + rbase + q], s);
    }
}

// ---------------- PV GEMM: 3-slot ring, depth-2 counted vmcnt, fine phases + setprio ----------------
// out = (P @ vT^T) * (1/rsum[row]); 128x192 tile, 8 waves, 12 useful MFMA/phase.
__global__ __launch_bounds__(512, 2) void gemm_pv(
    const u16* __restrict__ P, const u16* __restrict__ vT,
    const float* __restrict__ rsum, float* __restrict__ out)
{
  const int NJ = 3, CH = 5, gx = 16, gy = 4, NT = SEQ / 64;  // 32 K-tiles
  __shared__ u16 As[3][128][64];       // 48 KB
  __shared__ u16 Bs[3][NJ * 64][64];   // 72 KB
  const int tid = threadIdx.x;
  const int l   = tid & 63;
  const int wid = tid >> 6;
  const int wm  = wid >> 2;
  const int wn  = wid & 3;

  const int nwg = gridDim.x;           // 256
  const int cpx = nwg >> 3;
  const int bid = blockIdx.x;
  const int wg  = (bid & 7) * cpx + (bid >> 3);
  const int z   = wg / (gx * gy);
  const int rem = wg - z * gx * gy;
  const int by  = rem / gx;
  const int bx  = rem - by * gx;
  const int m0  = bx * 128;
  const int n0  = by * (NJ * 64);

  const u16* A  = P  + (size_t)z * SEQ * SEQ;
  const u16* BT = vT + (size_t)z * DV * SEQ;

  f32x4 acc[4][NJ] = {};

  const int lr = l >> 3;
  const int lc = ((l & 7) ^ lr) * 8;
  const int ca = wid * CH;

  auto STAGE = [&](int buf, int k0, int i0, int i1) {
#pragma unroll
    for (int i = 0; i < CH; ++i) {
      if (i < i0 || i >= i1) continue;
      int c = ca + i;
      if (c < 16) {
        const u16* src = A + (size_t)(m0 + c * 8 + lr) * SEQ + k0 + lc;
        __builtin_amdgcn_global_load_lds(
            (const __attribute__((address_space(1))) unsigned int*)src,
            (__attribute__((address_space(3))) unsigned int*)&As[buf][c * 8][0],
            16, 0, 0);
      } else {
        int cb = c - 16;
        const u16* src = BT + (size_t)(n0 + cb * 8 + lr) * SEQ + k0 + lc;
        __builtin_amdgcn_global_load_lds(
            (const __attribute__((address_space(1))) unsigned int*)src,
            (__attribute__((address_space(3))) unsigned int*)&Bs[buf][cb * 8][0],
            16, 0, 0);
      }
    }
  };

  STAGE(0, 0, 0, CH);
  STAGE(1, 64, 0, CH);
  int cur = 0;
  for (int t = 0; t < NT; ++t) {
    if (t == NT - 1) wait_vmcnt<0>(); else wait_vmcnt<CH>();
    __builtin_amdgcn_s_barrier();
    const int nxt2 = (cur + 2 >= 3) ? cur - 1 : cur + 2;
    const bool pf = (t + 2 < NT);
#pragma unroll
    for (int ks = 0; ks < 2; ++ks) {
      short8 af[4], bg[NJ];
#pragma unroll
      for (int i = 0; i < 4; ++i) {
        int row  = wm * 64 + i * 16 + (l & 15);
        int slot = (ks * 4 + (l >> 4)) ^ (row & 7);
        af[i] = *(const short8*)&As[cur][row][slot * 8];
      }
#pragma unroll
      for (int j = 0; j < NJ; ++j) {
        int row  = wn * (NJ * 16) + j * 16 + (l & 15);
        int slot = (ks * 4 + (l >> 4)) ^ (row & 7);
        bg[j] = *(const short8*)&Bs[cur][row][slot * 8];
      }
      if (pf) {
        if (ks == 0) STAGE(nxt2, (t + 2) * 64, 0, 3);
        else         STAGE(nxt2, (t + 2) * 64, 3, CH);
      }
      __builtin_amdgcn_s_setprio(1);
#pragma unroll
      for (int i = 0; i < 4; ++i)
#pragma unroll
        for (int j = 0; j < NJ; ++j)
          acc[i][j] = __builtin_amdgcn_mfma_f32_16x16x32_bf16(af[i], bg[j], acc[i][j], 0, 0, 0);
      __builtin_amdgcn_s_setprio(0);
    }
    cur = (cur + 1 == 3) ? 0 : cur + 1;
  }

  const int rbase = (l >> 4) * 4;
  const int cl    = l & 15;
  const float* rs_g = rsum + (size_t)z * SEQ;
#pragma unroll
  for (int i = 0; i < 4; ++i) {
    int row0 = m0 + wm * 64 + i * 16 + rbase;
    float4 rv = *(const float4*)&rs_g[row0];
    f32x4 rs;
    rs[0] = 1.0f / rv.x; rs[1] = 1.0f / rv.y; rs[2] = 1.0f / rv.z; rs[3] = 1.0f / rv.w;
#pragma unroll
    for (int j = 0; j < NJ; ++j) {
      int col = n0 + wn * (NJ * 16) + j * 16 + cl;
#pragma unroll
      for (int q = 0; q < 4; ++q)
        out[(size_t)z * SEQ * DV + (size_t)(row0 + q) * DV + col] = acc[i][j][q] * rs[q];
    }
  }
}

extern "C" void kernel_launch(void* const* d_in, const int* in_sizes, int n_in,
                              void* d_out, int out_size, void* d_ws, size_t ws_size,
                              hipStream_t stream) {
  const float* x  = (const float*)d_in[0];
  const float* Wq = (const float*)d_in[1];
  const float* bq = (const float*)d_in[2];
  const float* Wk = (const float*)d_in[3];
  const float* bk = (const float*)d_in[4];
  const float* Wv = (const float*)d_in[5];
  const float* bv = (const float*)d_in[6];
  float* out = (float*)d_out;

  size_t off = 0;
  auto alloc = [&](size_t bytes) -> void* {
    void* p = (char*)d_ws + off;
    off += (bytes + 255) & ~(size_t)255;
    return p;
  };
  u16*   xb    = (u16*)alloc((size_t)MTOT * DIN * 2);
  u16*   WbT   = (u16*)alloc((size_t)NQKV * DIN * 2);
  float* biasP = (float*)alloc(NQKV * 4);
  u16*   qk    = (u16*)alloc((size_t)MTOT * 256 * 2);
  u16*   vT    = (u16*)alloc((size_t)BATCH * DV * SEQ * 2);
  u16*   P     = (u16*)alloc((size_t)BATCH * SEQ * SEQ * 2);
  float* rsum  = (float*)alloc((size_t)MTOT * 4);
  if (off > ws_size) return;

  prep<<<dim3(6144 + 192 + 8), dim3(256), 0, stream>>>(x, xb, Wq, bq, Wk, bk, Wv, bv, WbT, biasP, rsum);

  // proj: [8192,1024] = xb @ WbT^T + bias; writes qk (n<256) and vT (transposed)
  gemm_proj<<<dim3(64 * 8), dim3(512), 0, stream>>>(xb, WbT, qk, vT, biasP);

  // P = exp(q_scaled @ k^T) per batch + partial row sums
  sgemm_exp<<<dim3(16 * 16 * BATCH), dim3(512), 0, stream>>>(qk, P, rsum);

  // out = (P @ vT^T) / rowsum per batch, fine-phase pipelined
  gemm_pv<<<dim3(16 * 4 * BATCH), dim3(512), 0, stream>>>(P, vT, rsum, out);
}